// Round 1
// 134.599 us; speedup vs baseline: 1.0015x; 1.0015x over previous
//
#include <hip/hip_runtime.h>
#include <hip/hip_bf16.h>

#define B_ 4
#define S_ 4096
#define D_ 1024
#define H_ 64
#define SCALE_ 0.125f
#define CFAC_ 0.180336884f   // SCALE * log2(e): exp(s*SCALE) == exp2(s*CFAC_)
#define WP_ 1056   // padded wq row stride (shorts)
#define SP_ 4224   // padded qT row stride (shorts)
#define NSPLIT 8

typedef __attribute__((ext_vector_type(8))) short bf16x8;
typedef __attribute__((ext_vector_type(4))) float f32x4;

// round-to-nearest-even f32 -> bf16 (finite inputs)
static __device__ __forceinline__ short f2bf(float f) {
    unsigned u = __builtin_bit_cast(unsigned, f);
    u += 0x7fffu + ((u >> 16) & 1u);
    return (short)(u >> 16);
}

// truncating pack: two f32 -> bf16x2 in one u32 (hi = f1, lo = f0)
static __device__ __forceinline__ unsigned pk_trunc(float f0, float f1) {
    return (__builtin_bit_cast(unsigned, f1) & 0xffff0000u)
         | (__builtin_bit_cast(unsigned, f0) >> 16);
}

// ---------------------------------------------------------------------------
// winit: wq f32 -> bf16 into padded [64][WP_] layout.
// ---------------------------------------------------------------------------
__global__ __launch_bounds__(256) void winit_kernel(
    const float* __restrict__ wq, short* __restrict__ wqb)
{
    const int i   = blockIdx.x * 256 + threadIdx.x;
    const int row = i >> 7;
    const int col = (i & 127) * 8;
    const float* s = wq + (size_t)row * D_ + col;
    bf16x8 v;
#pragma unroll
    for (int e = 0; e < 8; ++e) v[e] = f2bf(s[e]);
    *(bf16x8*)(wqb + (size_t)row * WP_ + col) = v;
}

// ---------------------------------------------------------------------------
// qproj: q = x @ wq^T (bf16 MFMA). Writes q (unscaled), qT (padded transpose)
// and qs_scaled = f2bf(q * CFAC_) for the flash exp2 fast path.
// ---------------------------------------------------------------------------
__global__ __launch_bounds__(256) void qproj_mfma(
    const float* __restrict__ x, const short* __restrict__ wqb,
    short* __restrict__ q, short* __restrict__ qT, short* __restrict__ qsb)
{
    __shared__ short xs[4][16][264];
    __shared__ float cs[4][16][68];
    __shared__ short qs[16][68];

    const int tid  = threadIdx.x;
    const int wave = tid >> 6;
    const int lane = tid & 63;
    const int quad = lane >> 4;
    const int lr   = lane & 15;
    const int row0 = blockIdx.x * 16;

    {
        const float* xp = x + (size_t)row0 * D_ + wave * 256 + lane * 4;
#pragma unroll
        for (int s = 0; s < 16; ++s) {
            const f32x4 v = *(const f32x4*)(xp + (size_t)s * D_);
            unsigned long long pk = 0;
#pragma unroll
            for (int e = 0; e < 4; ++e)
                pk |= (unsigned long long)(unsigned short)f2bf(v[e]) << (16 * e);
            *(unsigned long long*)&xs[wave][s][lane * 4] = pk;
        }
    }
    __syncthreads();

    f32x4 acc[4];
#pragma unroll
    for (int nb = 0; nb < 4; ++nb) acc[nb] = (f32x4){0.f, 0.f, 0.f, 0.f};

    const short* wp = wqb + (size_t)lr * WP_ + wave * 256 + quad * 8;
#pragma unroll
    for (int t = 0; t < 8; ++t) {
        const bf16x8 a = *(const bf16x8*)&xs[wave][lr][t * 32 + quad * 8];
#pragma unroll
        for (int nb = 0; nb < 4; ++nb) {
            const bf16x8 bb = *(const bf16x8*)(wp + (size_t)(nb * 16) * WP_ + t * 32);
            acc[nb] = __builtin_amdgcn_mfma_f32_16x16x32_bf16(a, bb, acc[nb], 0, 0, 0);
        }
    }

#pragma unroll
    for (int nb = 0; nb < 4; ++nb)
#pragma unroll
        for (int i = 0; i < 4; ++i)
            cs[wave][quad * 4 + i][nb * 16 + lr] = acc[nb][i];
    __syncthreads();

    const int r  = tid >> 4;
    const int c4 = (tid & 15) * 4;
    unsigned long long pv = 0, pw = 0;
#pragma unroll
    for (int j = 0; j < 4; ++j) {
        const float s = cs[0][r][c4 + j] + cs[1][r][c4 + j]
                      + cs[2][r][c4 + j] + cs[3][r][c4 + j];
        pv |= (unsigned long long)(unsigned short)f2bf(s) << (16 * j);
        pw |= (unsigned long long)(unsigned short)f2bf(s * CFAC_) << (16 * j);
    }
    *(unsigned long long*)(q   + (size_t)(row0 + r) * H_ + c4) = pv;
    *(unsigned long long*)(qsb + (size_t)(row0 + r) * H_ + c4) = pw;
    *(unsigned long long*)&qs[r][c4] = pv;
    __syncthreads();

    const int hh = tid >> 2;
    const int sj = (tid & 3) * 4;
    const int b  = row0 >> 12;
    const int sl = row0 & (S_ - 1);
    unsigned long long w = 0;
#pragma unroll
    for (int e = 0; e < 4; ++e)
        w |= (unsigned long long)(unsigned short)qs[sj + e][hh] << (16 * e);
    *(unsigned long long*)(qT + ((size_t)b * H_ + hh) * SP_ + sl + sj) = w;
}

// ---------------------------------------------------------------------------
// flash v7: v6 dataflow + 2 Q-sets per wave (A-fragment register reuse).
// Each kt/vt A-frag read from LDS feeds TWO MFMAs (two resident Q B-frags),
// halving the dominant LDS A-stream per FLOP. Block q-tile = 128 rows
// (4 waves x 32 q); NSPLIT 8 keeps grid at 1024 blocks (4/CU).
// S-accs processed in mt-pairs to cap live VGPRs (~16 for s[]).
// ---------------------------------------------------------------------------
__global__ __launch_bounds__(256, 4) void flash_mfma(
    const short* __restrict__ q, const short* __restrict__ qT,
    const short* __restrict__ qsb,
    float* __restrict__ opart, float* __restrict__ lbuf)
{
    __shared__ short kt[64 * 64];        // [k-row][d], granule-swizzled
    __shared__ short vt[64 * 64];        // [h][k-col], granule-swizzled
    __shared__ short plT[4][2][16][72];  // per-wave, per-Qset P^T as [q][k]

    const int tid  = threadIdx.x;
    const int w    = tid >> 6;
    const int lane = tid & 63;
    const int quad = lane >> 4;
    const int lr   = lane & 15;
    const int b    = blockIdx.y;
    const int q0   = blockIdx.x * 128;
    const int z    = blockIdx.z;
    const int slice = S_ / gridDim.z;
    const int kbase = z * slice;
    const short* qb  = q  + (size_t)b * S_ * H_;
    const short* qTb = qT + (size_t)b * H_ * SP_;

    // resident scaled-Q B-frags, 2 Q-sets: B[k=d][n=q=lr]
    bf16x8 qB[2][2];
#pragma unroll
    for (int qs = 0; qs < 2; ++qs) {
        const short* qr = qsb + (size_t)(b * S_ + q0 + w * 32 + qs * 16 + lr) * H_;
        qB[qs][0] = *(const bf16x8*)(qr + quad * 8);
        qB[qs][1] = *(const bf16x8*)(qr + 32 + quad * 8);
    }

    // ones A-fragment for the l-sum MFMA (bf16 1.0 = 0x3f80)
    bf16x8 ones;
#pragma unroll
    for (int e = 0; e < 8; ++e) ones[e] = (short)0x3f80;

    f32x4 o[2][4];
#pragma unroll
    for (int qs = 0; qs < 2; ++qs)
#pragma unroll
        for (int mt = 0; mt < 4; ++mt) o[qs][mt] = (f32x4){0.f, 0.f, 0.f, 0.f};
    f32x4 lsum[2];
    lsum[0] = (f32x4){0.f, 0.f, 0.f, 0.f};
    lsum[1] = (f32x4){0.f, 0.f, 0.f, 0.f};

    // staging: thread -> row srow, granule pair (32B), XOR-swizzled dest
    const int srow = tid >> 2;            // 0..63
    const int g0   = (tid & 3) * 2;
    const int sw0  = (g0 ^ (srow & 7)) * 8;
    const int sw1  = ((g0 + 1) ^ (srow & 7)) * 8;
    const short* gk = qb  + (size_t)(kbase + srow) * H_ + g0 * 8;
    const short* gv = qTb + (size_t)srow * SP_ + kbase + g0 * 8;

    uint4 pk0 = *(const uint4*)gk, pk1 = *(const uint4*)(gk + 8);
    uint4 pv0 = *(const uint4*)gv, pv1 = *(const uint4*)(gv + 8);

    const int iters = slice >> 6;
    for (int it = 0; it < iters; ++it) {
        __syncthreads();               // prev tiles consumed
        *(uint4*)&kt[srow * 64 + sw0] = pk0;
        *(uint4*)&kt[srow * 64 + sw1] = pk1;
        *(uint4*)&vt[srow * 64 + sw0] = pv0;
        *(uint4*)&vt[srow * 64 + sw1] = pv1;
        __syncthreads();               // staging visible
        if (it + 1 < iters) {
            gk += (size_t)64 * H_;
            gv += 64;
            pk0 = *(const uint4*)gk; pk1 = *(const uint4*)(gk + 8);
            pv0 = *(const uint4*)gv; pv1 = *(const uint4*)(gv + 8);
        }

        // ---- S^T = K (cQ)^T for both Q-sets, in mt-pairs; P^T = exp2 ----
#pragma unroll
        for (int mp = 0; mp < 2; ++mp) {
            f32x4 s[2][2];
            s[0][0] = (f32x4){0.f, 0.f, 0.f, 0.f};
            s[0][1] = (f32x4){0.f, 0.f, 0.f, 0.f};
            s[1][0] = (f32x4){0.f, 0.f, 0.f, 0.f};
            s[1][1] = (f32x4){0.f, 0.f, 0.f, 0.f};
#pragma unroll
            for (int c = 0; c < 2; ++c)
#pragma unroll
                for (int m2 = 0; m2 < 2; ++m2) {
                    const int row = (mp * 2 + m2) * 16 + lr;
                    const bf16x8 a = *(const bf16x8*)&kt[row * 64 + (((c * 4 + quad) ^ (row & 7)) * 8)];
                    s[0][m2] = __builtin_amdgcn_mfma_f32_16x16x32_bf16(a, qB[0][c], s[0][m2], 0, 0, 0);
                    s[1][m2] = __builtin_amdgcn_mfma_f32_16x16x32_bf16(a, qB[1][c], s[1][m2], 0, 0, 0);
                }
#pragma unroll
            for (int qs = 0; qs < 2; ++qs)
#pragma unroll
                for (int m2 = 0; m2 < 2; ++m2) {
                    const int mt = mp * 2 + m2;
                    const float p0 = __builtin_amdgcn_exp2f(s[qs][m2][0]);
                    const float p1 = __builtin_amdgcn_exp2f(s[qs][m2][1]);
                    const float p2 = __builtin_amdgcn_exp2f(s[qs][m2][2]);
                    const float p3 = __builtin_amdgcn_exp2f(s[qs][m2][3]);
                    unsigned lohi[2];
                    lohi[0] = pk_trunc(p0, p1);
                    lohi[1] = pk_trunc(p2, p3);
                    *(unsigned long long*)&plT[w][qs][lr][mt * 16 + quad * 4] =
                        *(unsigned long long*)lohi;
                }
        }

        // ---- O += V^T x P^T ; l += ones x P^T (matrix-pipe row sums) ----
#pragma unroll
        for (int c = 0; c < 2; ++c) {
            const bf16x8 pB0 = *(const bf16x8*)&plT[w][0][lr][c * 32 + quad * 8];
            const bf16x8 pB1 = *(const bf16x8*)&plT[w][1][lr][c * 32 + quad * 8];
            lsum[0] = __builtin_amdgcn_mfma_f32_16x16x32_bf16(ones, pB0, lsum[0], 0, 0, 0);
            lsum[1] = __builtin_amdgcn_mfma_f32_16x16x32_bf16(ones, pB1, lsum[1], 0, 0, 0);
#pragma unroll
            for (int mt = 0; mt < 4; ++mt) {
                const int row = mt * 16 + lr;
                const bf16x8 a = *(const bf16x8*)&vt[row * 64 + (((c * 4 + quad) ^ (row & 7)) * 8)];
                o[0][mt] = __builtin_amdgcn_mfma_f32_16x16x32_bf16(a, pB0, o[0][mt], 0, 0, 0);
                o[1][mt] = __builtin_amdgcn_mfma_f32_16x16x32_bf16(a, pB1, o[1][mt], 0, 0, 0);
            }
        }
    }

    // ---- write partials: O[q][h]; l = lsum[qs][0] (full row sum) ----
#pragma unroll
    for (int qs = 0; qs < 2; ++qs) {
        float* ob = opart + (((size_t)z * B_ + b) * S_ + q0 + w * 32 + qs * 16 + lr) * H_;
#pragma unroll
        for (int mt = 0; mt < 4; ++mt)
            *(f32x4*)(ob + mt * 16 + quad * 4) = o[qs][mt];
        if (quad == 0)
            lbuf[((size_t)z * B_ + b) * S_ + q0 + w * 32 + qs * 16 + lr] = lsum[qs][0];
    }
}

// ---------------------------------------------------------------------------
// combine: out[row][:] = sum_z opart[z][row][:] / sum_z lbuf[z][row]
// ---------------------------------------------------------------------------
__global__ __launch_bounds__(256) void combine_kernel(
    const float* __restrict__ opart, const float* __restrict__ lbuf,
    float* __restrict__ out, int nsplit)
{
    const int t   = blockIdx.x * 256 + threadIdx.x;   // 262144
    const int row = t >> 4;
    const int c4  = (t & 15) * 4;
    f32x4 acc = (f32x4){0.f, 0.f, 0.f, 0.f};
    float l = 0.0f;
    for (int z = 0; z < nsplit; ++z) {
        const f32x4 v = *(const f32x4*)(opart + ((size_t)z * (B_ * S_) + row) * H_ + c4);
        acc[0] += v[0]; acc[1] += v[1]; acc[2] += v[2]; acc[3] += v[3];
        l += lbuf[(size_t)z * (B_ * S_) + row];
    }
    const float r = 1.0f / l;
    acc[0] *= r; acc[1] *= r; acc[2] *= r; acc[3] *= r;
    *(f32x4*)(out + (size_t)row * H_ + c4) = acc;
}

extern "C" void kernel_launch(void* const* d_in, const int* in_sizes, int n_in,
                              void* d_out, int out_size, void* d_ws, size_t ws_size,
                              hipStream_t stream) {
    const float* x  = (const float*)d_in[0];   // [4,4096,1024] f32
    const float* wq = (const float*)d_in[1];   // [64,1024] f32
    float* out = (float*)d_out;                // [4,4096,64] f32

    const size_t off_qT  = 2097152;                               // q: 2 MiB
    const size_t off_wqb = off_qT + (size_t)B_ * H_ * SP_ * 2;    // qT padded
    const size_t off_qsb = off_wqb + (size_t)H_ * WP_ * 2;        // wqb padded
    const size_t off_op  = off_qsb + 2097152;                     // qsb 2 MiB
    short* qbuf = (short*)d_ws;
    short* qT   = (short*)((char*)d_ws + off_qT);
    short* wqb  = (short*)((char*)d_ws + off_wqb);
    short* qsb  = (short*)((char*)d_ws + off_qsb);

    const size_t per_split = (size_t)B_ * S_ * H_ * 4 + (size_t)B_ * S_ * 4;
    int nsplit = NSPLIT;
    while (nsplit > 1 && ws_size < off_op + (size_t)nsplit * per_split) nsplit >>= 1;
    float* opart = (float*)((char*)d_ws + off_op);
    float* lbuf  = (float*)((char*)d_ws + off_op + (size_t)nsplit * B_ * S_ * H_ * 4);

    winit_kernel<<<dim3(32), dim3(256), 0, stream>>>(wq, wqb);
    qproj_mfma<<<dim3((B_ * S_) / 16), dim3(256), 0, stream>>>(x, wqb, qbuf, qT, qsb);
    flash_mfma<<<dim3(S_ / 128, B_, nsplit), dim3(256), 0, stream>>>(qbuf, qT, qsb, opart, lbuf);
    combine_kernel<<<dim3(1024), dim3(256), 0, stream>>>(opart, lbuf, out, nsplit);
}

// Round 2
// 134.332 us; speedup vs baseline: 1.0035x; 1.0020x over previous
//
#include <hip/hip_runtime.h>
#include <hip/hip_bf16.h>

#define B_ 4
#define S_ 4096
#define D_ 1024
#define H_ 64
#define SCALE_ 0.125f
#define CFAC_ 0.180336884f   // SCALE * log2(e): exp(s*SCALE) == exp2(s*CFAC_)
#define WP_ 1056   // padded wq row stride (shorts)
#define SP_ 4224   // padded qT row stride (shorts)
#define NSPLIT 4

typedef __attribute__((ext_vector_type(8))) short bf16x8;
typedef __attribute__((ext_vector_type(4))) float f32x4;

// round-to-nearest-even f32 -> bf16 (finite inputs)
static __device__ __forceinline__ short f2bf(float f) {
    unsigned u = __builtin_bit_cast(unsigned, f);
    u += 0x7fffu + ((u >> 16) & 1u);
    return (short)(u >> 16);
}

// truncating pack: two f32 -> bf16x2 in one u32 (hi = f1, lo = f0)
static __device__ __forceinline__ unsigned pk_trunc(float f0, float f1) {
    return (__builtin_bit_cast(unsigned, f1) & 0xffff0000u)
         | (__builtin_bit_cast(unsigned, f0) >> 16);
}

// ---------------------------------------------------------------------------
// winit: wq f32 -> bf16 into padded [64][WP_] layout.
// ---------------------------------------------------------------------------
__global__ __launch_bounds__(256) void winit_kernel(
    const float* __restrict__ wq, short* __restrict__ wqb)
{
    const int i   = blockIdx.x * 256 + threadIdx.x;
    const int row = i >> 7;
    const int col = (i & 127) * 8;
    const float* s = wq + (size_t)row * D_ + col;
    bf16x8 v;
#pragma unroll
    for (int e = 0; e < 8; ++e) v[e] = f2bf(s[e]);
    *(bf16x8*)(wqb + (size_t)row * WP_ + col) = v;
}

// ---------------------------------------------------------------------------
// qproj: q = x @ wq^T (bf16 MFMA). Writes q (unscaled), qT (padded transpose)
// and qs_scaled = f2bf(q * CFAC_) for the flash exp2 fast path.
// ---------------------------------------------------------------------------
__global__ __launch_bounds__(256) void qproj_mfma(
    const float* __restrict__ x, const short* __restrict__ wqb,
    short* __restrict__ q, short* __restrict__ qT, short* __restrict__ qsb)
{
    __shared__ short xs[4][16][264];
    __shared__ float cs[4][16][68];
    __shared__ short qs[16][68];

    const int tid  = threadIdx.x;
    const int wave = tid >> 6;
    const int lane = tid & 63;
    const int quad = lane >> 4;
    const int lr   = lane & 15;
    const int row0 = blockIdx.x * 16;

    {
        const float* xp = x + (size_t)row0 * D_ + wave * 256 + lane * 4;
#pragma unroll
        for (int s = 0; s < 16; ++s) {
            const f32x4 v = *(const f32x4*)(xp + (size_t)s * D_);
            unsigned long long pk = 0;
#pragma unroll
            for (int e = 0; e < 4; ++e)
                pk |= (unsigned long long)(unsigned short)f2bf(v[e]) << (16 * e);
            *(unsigned long long*)&xs[wave][s][lane * 4] = pk;
        }
    }
    __syncthreads();

    f32x4 acc[4];
#pragma unroll
    for (int nb = 0; nb < 4; ++nb) acc[nb] = (f32x4){0.f, 0.f, 0.f, 0.f};

    const short* wp = wqb + (size_t)lr * WP_ + wave * 256 + quad * 8;
#pragma unroll
    for (int t = 0; t < 8; ++t) {
        const bf16x8 a = *(const bf16x8*)&xs[wave][lr][t * 32 + quad * 8];
#pragma unroll
        for (int nb = 0; nb < 4; ++nb) {
            const bf16x8 bb = *(const bf16x8*)(wp + (size_t)(nb * 16) * WP_ + t * 32);
            acc[nb] = __builtin_amdgcn_mfma_f32_16x16x32_bf16(a, bb, acc[nb], 0, 0, 0);
        }
    }

#pragma unroll
    for (int nb = 0; nb < 4; ++nb)
#pragma unroll
        for (int i = 0; i < 4; ++i)
            cs[wave][quad * 4 + i][nb * 16 + lr] = acc[nb][i];
    __syncthreads();

    const int r  = tid >> 4;
    const int c4 = (tid & 15) * 4;
    unsigned long long pv = 0, pw = 0;
#pragma unroll
    for (int j = 0; j < 4; ++j) {
        const float s = cs[0][r][c4 + j] + cs[1][r][c4 + j]
                      + cs[2][r][c4 + j] + cs[3][r][c4 + j];
        pv |= (unsigned long long)(unsigned short)f2bf(s) << (16 * j);
        pw |= (unsigned long long)(unsigned short)f2bf(s * CFAC_) << (16 * j);
    }
    *(unsigned long long*)(q   + (size_t)(row0 + r) * H_ + c4) = pv;
    *(unsigned long long*)(qsb + (size_t)(row0 + r) * H_ + c4) = pw;
    *(unsigned long long*)&qs[r][c4] = pv;
    __syncthreads();

    const int hh = tid >> 2;
    const int sj = (tid & 3) * 4;
    const int b  = row0 >> 12;
    const int sl = row0 & (S_ - 1);
    unsigned long long w = 0;
#pragma unroll
    for (int e = 0; e < 4; ++e)
        w |= (unsigned long long)(unsigned short)qs[sj + e][hh] << (16 * e);
    *(unsigned long long*)(qT + ((size_t)b * H_ + hh) * SP_ + sl + sj) = w;
}

// ---------------------------------------------------------------------------
// flash v8: v7 dataflow (2 Q-sets/wave, q-tile 128) + double-buffered kt/vt
// (ONE barrier per k-iter: compute buf[cur] -> write prefetched regs to
// buf[cur^1] -> issue loads for it+2 -> barrier) + NSPLIT 4 (512 blocks,
// 2 blocks/CU at 50 KB LDS; halves opart/combine traffic).
// Race note: in iter `it` only kt/vt[cur] and per-wave plT are read;
// buf[cur^1] was last consumed in iter it-1, sealed by that iter's barrier.
// ---------------------------------------------------------------------------
__global__ __launch_bounds__(256, 4) void flash_mfma(
    const short* __restrict__ q, const short* __restrict__ qT,
    const short* __restrict__ qsb,
    float* __restrict__ opart, float* __restrict__ lbuf)
{
    __shared__ short kt[2][64 * 64];     // [buf][k-row][d], granule-swizzled
    __shared__ short vt[2][64 * 64];     // [buf][h][k-col], granule-swizzled
    __shared__ short plT[4][2][16][72];  // per-wave, per-Qset P^T as [q][k]

    const int tid  = threadIdx.x;
    const int w    = tid >> 6;
    const int lane = tid & 63;
    const int quad = lane >> 4;
    const int lr   = lane & 15;
    const int b    = blockIdx.y;
    const int q0   = blockIdx.x * 128;
    const int z    = blockIdx.z;
    const int slice = S_ / gridDim.z;
    const int kbase = z * slice;
    const short* qb  = q  + (size_t)b * S_ * H_;
    const short* qTb = qT + (size_t)b * H_ * SP_;

    // resident scaled-Q B-frags, 2 Q-sets: B[k=d][n=q=lr]
    bf16x8 qB[2][2];
#pragma unroll
    for (int qs = 0; qs < 2; ++qs) {
        const short* qr = qsb + (size_t)(b * S_ + q0 + w * 32 + qs * 16 + lr) * H_;
        qB[qs][0] = *(const bf16x8*)(qr + quad * 8);
        qB[qs][1] = *(const bf16x8*)(qr + 32 + quad * 8);
    }

    // ones A-fragment for the l-sum MFMA (bf16 1.0 = 0x3f80)
    bf16x8 ones;
#pragma unroll
    for (int e = 0; e < 8; ++e) ones[e] = (short)0x3f80;

    f32x4 o[2][4];
#pragma unroll
    for (int qs = 0; qs < 2; ++qs)
#pragma unroll
        for (int mt = 0; mt < 4; ++mt) o[qs][mt] = (f32x4){0.f, 0.f, 0.f, 0.f};
    f32x4 lsum[2];
    lsum[0] = (f32x4){0.f, 0.f, 0.f, 0.f};
    lsum[1] = (f32x4){0.f, 0.f, 0.f, 0.f};

    // staging: thread -> row srow, granule pair (32B), XOR-swizzled dest
    const int srow = tid >> 2;            // 0..63
    const int g0   = (tid & 3) * 2;
    const int sw0  = (g0 ^ (srow & 7)) * 8;
    const int sw1  = ((g0 + 1) ^ (srow & 7)) * 8;
    const short* gk = qb  + (size_t)(kbase + srow) * H_ + g0 * 8;
    const short* gv = qTb + (size_t)srow * SP_ + kbase + g0 * 8;

    const int iters = slice >> 6;

    // prologue: tile 0 -> buf 0; prefetch tile 1 into regs
    uint4 pk0 = *(const uint4*)gk, pk1 = *(const uint4*)(gk + 8);
    uint4 pv0 = *(const uint4*)gv, pv1 = *(const uint4*)(gv + 8);
    *(uint4*)&kt[0][srow * 64 + sw0] = pk0;
    *(uint4*)&kt[0][srow * 64 + sw1] = pk1;
    *(uint4*)&vt[0][srow * 64 + sw0] = pv0;
    *(uint4*)&vt[0][srow * 64 + sw1] = pv1;
    if (iters > 1) {
        gk += (size_t)64 * H_;
        gv += 64;
        pk0 = *(const uint4*)gk; pk1 = *(const uint4*)(gk + 8);
        pv0 = *(const uint4*)gv; pv1 = *(const uint4*)(gv + 8);
    }
    __syncthreads();               // buf0 visible

    for (int it = 0; it < iters; ++it) {
        const int cur = it & 1;
        const short* ktc = kt[cur];
        const short* vtc = vt[cur];

        // ---- S^T = K (cQ)^T for both Q-sets, in mt-pairs; P^T = exp2 ----
#pragma unroll
        for (int mp = 0; mp < 2; ++mp) {
            f32x4 s[2][2];
            s[0][0] = (f32x4){0.f, 0.f, 0.f, 0.f};
            s[0][1] = (f32x4){0.f, 0.f, 0.f, 0.f};
            s[1][0] = (f32x4){0.f, 0.f, 0.f, 0.f};
            s[1][1] = (f32x4){0.f, 0.f, 0.f, 0.f};
#pragma unroll
            for (int c = 0; c < 2; ++c)
#pragma unroll
                for (int m2 = 0; m2 < 2; ++m2) {
                    const int row = (mp * 2 + m2) * 16 + lr;
                    const bf16x8 a = *(const bf16x8*)&ktc[row * 64 + (((c * 4 + quad) ^ (row & 7)) * 8)];
                    s[0][m2] = __builtin_amdgcn_mfma_f32_16x16x32_bf16(a, qB[0][c], s[0][m2], 0, 0, 0);
                    s[1][m2] = __builtin_amdgcn_mfma_f32_16x16x32_bf16(a, qB[1][c], s[1][m2], 0, 0, 0);
                }
#pragma unroll
            for (int qs = 0; qs < 2; ++qs)
#pragma unroll
                for (int m2 = 0; m2 < 2; ++m2) {
                    const int mt = mp * 2 + m2;
                    const float p0 = __builtin_amdgcn_exp2f(s[qs][m2][0]);
                    const float p1 = __builtin_amdgcn_exp2f(s[qs][m2][1]);
                    const float p2 = __builtin_amdgcn_exp2f(s[qs][m2][2]);
                    const float p3 = __builtin_amdgcn_exp2f(s[qs][m2][3]);
                    unsigned lohi[2];
                    lohi[0] = pk_trunc(p0, p1);
                    lohi[1] = pk_trunc(p2, p3);
                    *(unsigned long long*)&plT[w][qs][lr][mt * 16 + quad * 4] =
                        *(unsigned long long*)lohi;
                }
        }

        // ---- O += V^T x P^T ; l += ones x P^T (matrix-pipe row sums) ----
#pragma unroll
        for (int c = 0; c < 2; ++c) {
            const bf16x8 pB0 = *(const bf16x8*)&plT[w][0][lr][c * 32 + quad * 8];
            const bf16x8 pB1 = *(const bf16x8*)&plT[w][1][lr][c * 32 + quad * 8];
            lsum[0] = __builtin_amdgcn_mfma_f32_16x16x32_bf16(ones, pB0, lsum[0], 0, 0, 0);
            lsum[1] = __builtin_amdgcn_mfma_f32_16x16x32_bf16(ones, pB1, lsum[1], 0, 0, 0);
#pragma unroll
            for (int mt = 0; mt < 4; ++mt) {
                const int row = mt * 16 + lr;
                const bf16x8 a = *(const bf16x8*)&vtc[row * 64 + (((c * 4 + quad) ^ (row & 7)) * 8)];
                o[0][mt] = __builtin_amdgcn_mfma_f32_16x16x32_bf16(a, pB0, o[0][mt], 0, 0, 0);
                o[1][mt] = __builtin_amdgcn_mfma_f32_16x16x32_bf16(a, pB1, o[1][mt], 0, 0, 0);
            }
        }

        // ---- stage tile it+1 into buf[cur^1]; prefetch tile it+2 ----
        if (it + 1 < iters) {
            const int nxt = cur ^ 1;
            *(uint4*)&kt[nxt][srow * 64 + sw0] = pk0;
            *(uint4*)&kt[nxt][srow * 64 + sw1] = pk1;
            *(uint4*)&vt[nxt][srow * 64 + sw0] = pv0;
            *(uint4*)&vt[nxt][srow * 64 + sw1] = pv1;
            if (it + 2 < iters) {
                gk += (size_t)64 * H_;
                gv += 64;
                pk0 = *(const uint4*)gk; pk1 = *(const uint4*)(gk + 8);
                pv0 = *(const uint4*)gv; pv1 = *(const uint4*)(gv + 8);
            }
        }
        __syncthreads();           // staging visible; buf[cur] free next iter
    }

    // ---- write partials: O[q][h]; l = lsum[qs][0] (full row sum) ----
#pragma unroll
    for (int qs = 0; qs < 2; ++qs) {
        float* ob = opart + (((size_t)z * B_ + b) * S_ + q0 + w * 32 + qs * 16 + lr) * H_;
#pragma unroll
        for (int mt = 0; mt < 4; ++mt)
            *(f32x4*)(ob + mt * 16 + quad * 4) = o[qs][mt];
        if (quad == 0)
            lbuf[((size_t)z * B_ + b) * S_ + q0 + w * 32 + qs * 16 + lr] = lsum[qs][0];
    }
}

// ---------------------------------------------------------------------------
// combine: out[row][:] = sum_z opart[z][row][:] / sum_z lbuf[z][row]
// ---------------------------------------------------------------------------
__global__ __launch_bounds__(256) void combine_kernel(
    const float* __restrict__ opart, const float* __restrict__ lbuf,
    float* __restrict__ out, int nsplit)
{
    const int t   = blockIdx.x * 256 + threadIdx.x;   // 262144
    const int row = t >> 4;
    const int c4  = (t & 15) * 4;
    f32x4 acc = (f32x4){0.f, 0.f, 0.f, 0.f};
    float l = 0.0f;
    for (int z = 0; z < nsplit; ++z) {
        const f32x4 v = *(const f32x4*)(opart + ((size_t)z * (B_ * S_) + row) * H_ + c4);
        acc[0] += v[0]; acc[1] += v[1]; acc[2] += v[2]; acc[3] += v[3];
        l += lbuf[(size_t)z * (B_ * S_) + row];
    }
    const float r = 1.0f / l;
    acc[0] *= r; acc[1] *= r; acc[2] *= r; acc[3] *= r;
    *(f32x4*)(out + (size_t)row * H_ + c4) = acc;
}

extern "C" void kernel_launch(void* const* d_in, const int* in_sizes, int n_in,
                              void* d_out, int out_size, void* d_ws, size_t ws_size,
                              hipStream_t stream) {
    const float* x  = (const float*)d_in[0];   // [4,4096,1024] f32
    const float* wq = (const float*)d_in[1];   // [64,1024] f32
    float* out = (float*)d_out;                // [4,4096,64] f32

    const size_t off_qT  = 2097152;                               // q: 2 MiB
    const size_t off_wqb = off_qT + (size_t)B_ * H_ * SP_ * 2;    // qT padded
    const size_t off_qsb = off_wqb + (size_t)H_ * WP_ * 2;        // wqb padded
    const size_t off_op  = off_qsb + 2097152;                     // qsb 2 MiB
    short* qbuf = (short*)d_ws;
    short* qT   = (short*)((char*)d_ws + off_qT);
    short* wqb  = (short*)((char*)d_ws + off_wqb);
    short* qsb  = (short*)((char*)d_ws + off_qsb);

    const size_t per_split = (size_t)B_ * S_ * H_ * 4 + (size_t)B_ * S_ * 4;
    int nsplit = NSPLIT;
    while (nsplit > 1 && ws_size < off_op + (size_t)nsplit * per_split) nsplit >>= 1;
    float* opart = (float*)((char*)d_ws + off_op);
    float* lbuf  = (float*)((char*)d_ws + off_op + (size_t)nsplit * B_ * S_ * H_ * 4);

    winit_kernel<<<dim3(32), dim3(256), 0, stream>>>(wq, wqb);
    qproj_mfma<<<dim3((B_ * S_) / 16), dim3(256), 0, stream>>>(x, wqb, qbuf, qT, qsb);
    flash_mfma<<<dim3(S_ / 128, B_, nsplit), dim3(256), 0, stream>>>(qbuf, qT, qsb, opart, lbuf);
    combine_kernel<<<dim3(1024), dim3(256), 0, stream>>>(opart, lbuf, out, nsplit);
}